// Round 1
// baseline (5967.135 us; speedup 1.0000x reference)
//
#include <hip/hip_runtime.h>
#include <hip/hip_bf16.h>
#include <math.h>

// ---------------------------------------------------------------------------
// LSTM encoder-decoder model, fp32 baseline.
//  enc: 256 steps, z = [x_t|h] @ [W;U], softmax gates (act=softmax!)
//  dec: input constant (RepeatVector) -> xW precomputed once; 64 steps x 2 dirs
//  dense: [B*T,512] @ [512,16]
// ---------------------------------------------------------------------------

#define WS_F(ofs) (ws + (ofs))

// ws layout (float offsets)
#define OFS_HENC   0u          // 256*512
#define OFS_CENC   131072u     // 256*512
#define OFS_HF     262144u     // 256*256
#define OFS_CF     327680u
#define OFS_HB     393216u
#define OFS_CB     458752u
#define OFS_ZPART  524288u     // 4 * 256*2048
#define OFS_XW     2621440u    // 256*2048
#define OFS_HSEQ   3145728u    // 256*64*512
#define WS_FLOATS  11534336u

// ---------------------------------------------------------------------------
// Generic partial GEMM: zpart[ks][256][2048] += A[256 x K_split] * B
// MODE 0 (encoder step): A = concat(x_t [64], h_enc [512]); B = concat(W,U) ld 2048
// MODE 1 (dec input proj): A = h_enc (lda 512); B = dec_{f,b}_kernel by n-col, ld 1024
// MODE 2 (dec step): A = h_f / h_b by n-col (lda 256); B = dec_{f,b}_rec, ld 1024
// Tiling: BM=32, BN=64, BK=16, 128 threads, 4x4 per thread.
// ---------------------------------------------------------------------------
template <int MODE>
__global__ __launch_bounds__(128) void gemm_part(
    const float* __restrict__ P0, const float* __restrict__ P1,
    const float* __restrict__ P2, const float* __restrict__ P3,
    float* __restrict__ zpart, int t)
{
    constexpr int SPLIT = (MODE == 0) ? 144 : 128;
    const int n0 = blockIdx.x * 64;
    const int m0 = blockIdx.y * 32;
    const int kbeg = blockIdx.z * SPLIT;
    const int kend = kbeg + SPLIT;

    __shared__ __align__(16) float As[16][36];  // [k][m], padded
    __shared__ __align__(16) float Bs[16][68];  // [k][n], padded

    const int tid = threadIdx.x;
    const int am  = tid & 31, akq = tid >> 5;   // A loader: row, k-quad
    const int bc4 = tid & 15, bkr = tid >> 4;   // B loader: col-quad, k-row
    const int cr  = tid >> 4, cc  = tid & 15;   // compute: 8 x 16 thread grid

    float acc[4][4] = {};

    for (int kb = kbeg; kb < kend; kb += 16) {
        // ---- load A tile (32 rows x 16 k), transposed into LDS ----
        {
            const int kg = kb + akq * 4;
            const float* src;
            if (MODE == 0) {
                src = (kg < 64) ? (P0 + (size_t)(m0 + am) * 16384 + t * 64 + kg)
                                : (P1 + (size_t)(m0 + am) * 512 + (kg - 64));
            } else if (MODE == 1) {
                src = P0 + (size_t)(m0 + am) * 512 + kg;
            } else {
                const float* hp = (n0 < 1024) ? P0 : P1;
                src = hp + (size_t)(m0 + am) * 256 + kg;
            }
            const float4 av = *(const float4*)src;
            As[akq * 4 + 0][am] = av.x;
            As[akq * 4 + 1][am] = av.y;
            As[akq * 4 + 2][am] = av.z;
            As[akq * 4 + 3][am] = av.w;
        }
        // ---- load B tile (16 k x 64 cols) ----
        #pragma unroll
        for (int p = 0; p < 2; ++p) {
            const int kg = kb + p * 8 + bkr;
            const float* src;
            if (MODE == 0) {
                src = (kg < 64) ? (P2 + (size_t)kg * 2048 + n0)
                                : (P3 + (size_t)(kg - 64) * 2048 + n0);
            } else {
                const float* bp = (n0 < 1024) ? P2 : P3;
                const int nn = (n0 < 1024) ? n0 : (n0 - 1024);
                src = bp + (size_t)kg * 1024 + nn;
            }
            *(float4*)&Bs[p * 8 + bkr][bc4 * 4] = *(const float4*)(src + bc4 * 4);
        }
        __syncthreads();
        #pragma unroll
        for (int kk = 0; kk < 16; ++kk) {
            const float4 av = *(const float4*)&As[kk][cr * 4];
            const float4 bv = *(const float4*)&Bs[kk][cc * 4];
            const float aa[4] = {av.x, av.y, av.z, av.w};
            const float bb[4] = {bv.x, bv.y, bv.z, bv.w};
            #pragma unroll
            for (int i = 0; i < 4; ++i)
                #pragma unroll
                for (int j = 0; j < 4; ++j)
                    acc[i][j] = fmaf(aa[i], bb[j], acc[i][j]);
        }
        __syncthreads();
    }

    float* zp = zpart + (size_t)blockIdx.z * 524288;
    #pragma unroll
    for (int i = 0; i < 4; ++i) {
        float4 v = {acc[i][0], acc[i][1], acc[i][2], acc[i][3]};
        *(float4*)(zp + (size_t)(m0 + cr * 4 + i) * 2048 + n0 + cc * 4) = v;
    }
}

// ---------------------------------------------------------------------------
// block reductions (256 threads = 4 waves)
// ---------------------------------------------------------------------------
__device__ __forceinline__ float blk_max(float v, float* red) {
    #pragma unroll
    for (int m = 32; m; m >>= 1) v = fmaxf(v, __shfl_xor(v, m, 64));
    const int wid = threadIdx.x >> 6;
    if ((threadIdx.x & 63) == 0) red[wid] = v;
    __syncthreads();
    v = fmaxf(fmaxf(red[0], red[1]), fmaxf(red[2], red[3]));
    __syncthreads();
    return v;
}
__device__ __forceinline__ float blk_sum(float v, float* red) {
    #pragma unroll
    for (int m = 32; m; m >>= 1) v += __shfl_xor(v, m, 64);
    const int wid = threadIdx.x >> 6;
    if ((threadIdx.x & 63) == 0) red[wid] = v;
    __syncthreads();
    v = red[0] + red[1] + red[2] + red[3];
    __syncthreads();
    return v;
}
__device__ __forceinline__ float sigm(float x) { return 1.0f / (1.0f + __expf(-x)); }

// ---------------------------------------------------------------------------
// encoder gate update: one block per batch row; softmax over g and over c.
// ---------------------------------------------------------------------------
__global__ __launch_bounds__(256) void enc_update(
    const float* __restrict__ zpart, const float* __restrict__ bias,
    float* __restrict__ h, float* __restrict__ c)
{
    __shared__ float red[4];
    const int b = blockIdx.x, tid = threadIdx.x;
    const float* zb = zpart + (size_t)b * 2048;

    float zi[2], zf[2], zg[2], zo[2];
    #pragma unroll
    for (int j = 0; j < 2; ++j) {
        const int u = tid + j * 256;
        float vi = bias[u], vf = bias[512 + u], vg = bias[1024 + u], vo = bias[1536 + u];
        #pragma unroll
        for (int s = 0; s < 4; ++s) {
            const float* z = zb + (size_t)s * 524288;
            vi += z[u]; vf += z[u + 512]; vg += z[u + 1024]; vo += z[u + 1536];
        }
        zi[j] = vi; zf[j] = vf; zg[j] = vg; zo[j] = vo;
    }
    // softmax over g (512 units)
    const float mx = blk_max(fmaxf(zg[0], zg[1]), red);
    float e[2] = {__expf(zg[0] - mx), __expf(zg[1] - mx)};
    const float inv = 1.0f / blk_sum(e[0] + e[1], red);

    float cn[2], so[2];
    #pragma unroll
    for (int j = 0; j < 2; ++j) {
        const int u = tid + j * 256;
        so[j] = sigm(zo[j]);
        const float cv = sigm(zf[j]) * c[(size_t)b * 512 + u] + sigm(zi[j]) * (e[j] * inv);
        c[(size_t)b * 512 + u] = cv;
        cn[j] = cv;
    }
    // softmax over new c (512 units)
    const float mx2 = blk_max(fmaxf(cn[0], cn[1]), red);
    float ec[2] = {__expf(cn[0] - mx2), __expf(cn[1] - mx2)};
    const float inv2 = 1.0f / blk_sum(ec[0] + ec[1], red);
    #pragma unroll
    for (int j = 0; j < 2; ++j) {
        const int u = tid + j * 256;
        h[(size_t)b * 512 + u] = so[j] * ec[j] * inv2;
    }
}

// ---------------------------------------------------------------------------
// dec input-projection reduce + bias fold: xw = sum of 4 partials + bias
// ---------------------------------------------------------------------------
__global__ __launch_bounds__(256) void xw_reduce(
    const float* __restrict__ zpart, const float* __restrict__ bf,
    const float* __restrict__ bb, float* __restrict__ xw)
{
    const int i = blockIdx.x * 256 + threadIdx.x;  // 524288 total
    const int n = i & 2047;
    const float bias = (n < 1024) ? bf[n] : bb[n - 1024];
    xw[i] = zpart[i] + zpart[i + 524288] + zpart[i + 2 * 524288] + zpart[i + 3 * 524288] + bias;
}

// ---------------------------------------------------------------------------
// decoder gate update (elementwise tanh), both directions, writes hseq
// ---------------------------------------------------------------------------
__global__ __launch_bounds__(256) void dec_update(
    const float* __restrict__ zpart, const float* __restrict__ xw,
    float* __restrict__ hf, float* __restrict__ cf,
    float* __restrict__ hb, float* __restrict__ cb,
    float* __restrict__ hseq, int step)
{
    const int idx = blockIdx.x * 256 + threadIdx.x;  // 131072 = 2*256*256
    const int u = idx & 255;
    const int b = (idx >> 8) & 255;
    const int dir = idx >> 16;
    const size_t base = (size_t)b * 2048 + dir * 1024 + u;

    const float zi = xw[base]       + zpart[base]       + zpart[524288 + base];
    const float zf = xw[base + 256] + zpart[base + 256] + zpart[524288 + base + 256];
    const float zg = xw[base + 512] + zpart[base + 512] + zpart[524288 + base + 512];
    const float zo = xw[base + 768] + zpart[base + 768] + zpart[524288 + base + 768];

    float* c = dir ? cb : cf;
    float* h = dir ? hb : hf;
    const size_t hi = (size_t)b * 256 + u;
    const float cv = sigm(zf) * c[hi] + sigm(zi) * tanhf(zg);
    c[hi] = cv;
    const float hv = sigm(zo) * tanhf(cv);
    h[hi] = hv;
    const int tt = dir ? (63 - step) : step;
    hseq[((size_t)b * 64 + tt) * 512 + dir * 256 + u] = hv;
}

// ---------------------------------------------------------------------------
// final dense: out[b][t][f] = hseq[b][t][:] . Dk[:,f] + Db[f]
// ---------------------------------------------------------------------------
__global__ __launch_bounds__(256) void dense_kernel(
    const float* __restrict__ hseq, const float* __restrict__ Dk,
    const float* __restrict__ Db, float* __restrict__ out)
{
    __shared__ float dk[8192];  // 512 x 16
    for (int i = threadIdx.x; i < 8192; i += 256) dk[i] = Dk[i];
    __syncthreads();
    const int f = threadIdx.x & 15;
    const int bt = blockIdx.x * 16 + (threadIdx.x >> 4);
    const float* hs = hseq + (size_t)bt * 512;
    float acc = Db[f];
    #pragma unroll 4
    for (int k = 0; k < 512; k += 4) {
        const float4 hv = *(const float4*)(hs + k);
        acc += hv.x * dk[(k + 0) * 16 + f] + hv.y * dk[(k + 1) * 16 + f]
             + hv.z * dk[(k + 2) * 16 + f] + hv.w * dk[(k + 3) * 16 + f];
    }
    out[(size_t)bt * 16 + f] = acc;
}

__global__ __launch_bounds__(256) void zero_state(float* __restrict__ p)
{
    const int i4 = (blockIdx.x * 256 + threadIdx.x) * 4;  // 524288 floats total
    *(float4*)(p + i4) = float4{0.f, 0.f, 0.f, 0.f};
}

// ---------------------------------------------------------------------------
extern "C" void kernel_launch(void* const* d_in, const int* in_sizes, int n_in,
                              void* d_out, int out_size, void* d_ws, size_t ws_size,
                              hipStream_t stream)
{
    const float* x    = (const float*)d_in[0];   // [256][256][64]
    const float* encW = (const float*)d_in[1];   // [64][2048]
    const float* encU = (const float*)d_in[2];   // [512][2048]
    const float* encB = (const float*)d_in[3];   // [2048]
    const float* dfK  = (const float*)d_in[4];   // [512][1024]
    const float* dfU  = (const float*)d_in[5];   // [256][1024]
    const float* dfB  = (const float*)d_in[6];   // [1024]
    const float* dbK  = (const float*)d_in[7];   // [512][1024]
    const float* dbU  = (const float*)d_in[8];   // [256][1024]
    const float* dbB  = (const float*)d_in[9];   // [1024]
    const float* dK   = (const float*)d_in[10];  // [512][16]
    const float* dB   = (const float*)d_in[11];  // [16]

    if (ws_size < WS_FLOATS * sizeof(float)) return;  // need ~46 MB scratch

    float* ws    = (float*)d_ws;
    float* hEnc  = WS_F(OFS_HENC);
    float* cEnc  = WS_F(OFS_CENC);
    float* hF    = WS_F(OFS_HF);
    float* cF    = WS_F(OFS_CF);
    float* hB    = WS_F(OFS_HB);
    float* cB    = WS_F(OFS_CB);
    float* zpart = WS_F(OFS_ZPART);
    float* xw    = WS_F(OFS_XW);
    float* hseq  = WS_F(OFS_HSEQ);

    // zero h/c states (first 524288 floats of ws, laid out contiguously)
    zero_state<<<512, 256, 0, stream>>>(ws);

    // ---- encoder: 256 sequential steps ----
    for (int t = 0; t < 256; ++t) {
        gemm_part<0><<<dim3(32, 8, 4), 128, 0, stream>>>(x, hEnc, encW, encU, zpart, t);
        enc_update<<<256, 256, 0, stream>>>(zpart, encB, hEnc, cEnc);
    }

    // ---- decoder input projection (input constant across time) ----
    gemm_part<1><<<dim3(32, 8, 4), 128, 0, stream>>>(hEnc, nullptr, dfK, dbK, zpart, 0);
    xw_reduce<<<2048, 256, 0, stream>>>(zpart, dfB, dbB, xw);

    // ---- decoder: 64 steps, both directions ----
    for (int s = 0; s < 64; ++s) {
        gemm_part<2><<<dim3(32, 8, 2), 128, 0, stream>>>(hF, hB, dfU, dbU, zpart, 0);
        dec_update<<<512, 256, 0, stream>>>(zpart, xw, hF, cF, hB, cB, hseq, s);
    }

    // ---- dense head ----
    dense_kernel<<<1024, 256, 0, stream>>>(hseq, dK, dB, (float*)d_out);
}